// Round 2
// baseline (850.727 us; speedup 1.0000x reference)
//
#include <hip/hip_runtime.h>

// Problem constants (from the JAX reference)
constexpr unsigned B = 4, H = 32, T = 4096, T_NEW = 16, D = 128;
constexpr unsigned SINK = 4, WINDOW = 4096;
constexpr unsigned T_OUT = SINK + WINDOW;          // 4100
constexpr unsigned BH = B * H;                     // 128
constexpr unsigned F4_PER_ROW = D / 4;             // 32 float4 per row (512 B)
constexpr unsigned ROWS_PER_TENSOR = BH * T_OUT;   // 524,800
constexpr unsigned F4_PER_TENSOR = ROWS_PER_TENSOR * F4_PER_ROW; // 16,793,600
// Region boundaries along the output time axis
constexpr unsigned WIN_END = SINK + (T - T_NEW);   // 4084; t >= WIN_END reads *_new
constexpr unsigned SHIFT = T_NEW - SINK;           // 12; old-cache row = t + 12

__global__ __launch_bounds__(256) void kv_evict_copy(
    const float4* __restrict__ K, const float4* __restrict__ V,
    const float4* __restrict__ Kn, const float4* __restrict__ Vn,
    float4* __restrict__ out)
{
    // blockIdx.y = 0 -> K half, 1 -> V half (branch hoisted out of the loop)
    const float4* __restrict__ src_old = blockIdx.y ? V  : K;
    const float4* __restrict__ src_new = blockIdx.y ? Vn : Kn;
    float4* __restrict__ dst = out + (size_t)blockIdx.y * F4_PER_TENSOR;

    unsigned idx = blockIdx.x * blockDim.x + threadIdx.x;
    const unsigned stride = gridDim.x * blockDim.x;
    for (; idx < F4_PER_TENSOR; idx += stride) {
        const unsigned c   = idx & (F4_PER_ROW - 1);   // float4 within row
        const unsigned row = idx >> 5;                 // row within tensor
        const unsigned bh  = row / T_OUT;              // compiler emits magic-mul
        const unsigned t   = row - bh * T_OUT;         // output time index

        float4 val;
        if (t < SINK) {
            val = src_old[(bh * T + t) * F4_PER_ROW + c];            // sink rows
        } else if (t < WIN_END) {
            val = src_old[(bh * T + (t + SHIFT)) * F4_PER_ROW + c];  // window body
        } else {
            val = src_new[(bh * T_NEW + (t - WIN_END)) * F4_PER_ROW + c]; // new tail
        }
        dst[idx] = val;
    }
}

extern "C" void kernel_launch(void* const* d_in, const int* in_sizes, int n_in,
                              void* d_out, int out_size, void* d_ws, size_t ws_size,
                              hipStream_t stream)
{
    const float4* K  = (const float4*)d_in[0];
    const float4* V  = (const float4*)d_in[1];
    const float4* Kn = (const float4*)d_in[2];
    const float4* Vn = (const float4*)d_in[3];
    float4* out = (float4*)d_out;

    dim3 block(256);
    dim3 grid(4096, 2);   // x: grid-stride over one tensor half; y: K/V select
    kv_evict_copy<<<grid, block, 0, stream>>>(K, V, Kn, Vn, out);
}